// Round 8
// baseline (2527.020 us; speedup 1.0000x reference)
//
#include <hip/hip_runtime.h>
#include <stdint.h>

#define B_   128
#define T_   256
#define IN_  512
#define H_   1024
#define NG_  4096   // 4*H (gate-interleaved rows)
#define KC_  1536   // IN+H
#define OUT_ 512
#define NBLK 256    // 8 groups x 32 blocks
#define NTHR 1024   // 16 waves: 8 n-subtiles x 2 K-halves

typedef __bf16 bf16x8 __attribute__((ext_vector_type(8)));
typedef float  f32x4  __attribute__((ext_vector_type(4)));

__device__ __forceinline__ ushort f2bf(float f) {
    union { float f; uint32_t u; } v; v.f = f;
    uint32_t u = v.u;
    return (ushort)((u + 0x7FFFu + ((u >> 16) & 1u)) >> 16);  // RNE
}

__device__ __forceinline__ f32x4 mfma16(bf16x8 a, bf16x8 b, f32x4 c) {
    return __builtin_amdgcn_mfma_f32_16x16x32_bf16(a, b, c, 0, 0, 0);
}

__device__ __forceinline__ float sigf(float x) {
    return 1.f / (1.f + __expf(-x));
}

// ---------------- prep kernels ----------------

__global__ void prep_w(const float* __restrict__ Wf, const float* __restrict__ Wi,
                       const float* __restrict__ Wc, const float* __restrict__ Wo,
                       ushort* __restrict__ Wcat) {
    int row = blockIdx.x;            // 0..4095 (= 4*j+g)
    int j = row >> 2, g = row & 3;
    const float* W = (g == 0) ? Wf : (g == 1) ? Wi : (g == 2) ? Wc : Wo;
    for (int k = threadIdx.x; k < KC_; k += 256)
        Wcat[(size_t)row * KC_ + k] = f2bf(W[(size_t)j * KC_ + k]);
}

__global__ void prep_bias(const float* __restrict__ bf_, const float* __restrict__ bi_,
                          const float* __restrict__ bc_, const float* __restrict__ bo_,
                          float* __restrict__ bias) {
    int idx = blockIdx.x * 256 + threadIdx.x;  // 16 blocks -> 4096
    int j = idx >> 2, g = idx & 3;
    const float* b = (g == 0) ? bf_ : (g == 1) ? bi_ : (g == 2) ? bc_ : bo_;
    bias[idx] = b[j];
}

__global__ void prep_wout(const float* __restrict__ W, ushort* __restrict__ Wb) {
    int row = blockIdx.x;  // 512
    for (int k = threadIdx.x; k < H_; k += 256)
        Wb[(size_t)row * H_ + k] = f2bf(W[(size_t)row * H_ + k]);
}

__global__ void prep_x(const float* __restrict__ x, ushort* __restrict__ xT) {
    int bid = blockIdx.x;            // t*128 + b
    int t = bid >> 7, b = bid & 127;
    const float* src = x  + ((size_t)b * T_ + t) * IN_;
    ushort*      dst = xT + ((size_t)t * B_ + b) * IN_;
    for (int k = threadIdx.x; k < IN_; k += 256) dst[k] = f2bf(src[k]);
}

__global__ void prep_zero(ushort* __restrict__ hs0, unsigned int* __restrict__ flags) {
    int idx = blockIdx.x * 256 + threadIdx.x;  // 512*256 = 131072 = B_*H_
    hs0[idx] = 0;
    if (idx < NBLK) flags[idx] = 0u;
}

// ---------------- persistent LSTM kernel ----------------
// 256 blocks x 1024 threads (16 waves), structurally 1 block/CU (16 waves x
// 128 VGPR = full CU register file). Group = bx&7 (XCD-affine), sub = bx>>3;
// group owns batch rows [grp*16,+16); block owns gate cols [sub*128,+128).
// Wave wv: nh = wv&7 (16-col subtile), kh = wv>>3 (K-half, INTERLEAVED even/
// odd 32-chunks so the x-part is balanced across kh). breg[24] = 96 VGPRs of
// W per lane — r4-r6 lesson: this compiler remats/spills any read-only loads
// above ~128 live VGPRs under every hint; 1024-thr blocks make 128 a hard
// architectural cap and 96+working fits under it, so W is finally resident.
// Cross-kh reduction via padded LDS tile. Coherence (r5): no fences; h and
// flags via relaxed agent-scope atomics (LLC-coherent, L1/L2 bypass);
// ordering = syncthreads vmcnt-drain before flag store + reader control-dep.

__global__ void __launch_bounds__(NTHR, 4)
lstm_persist(const ushort* __restrict__ xT,
             const ushort* __restrict__ Wcat,
             const float* __restrict__ bias,
             ushort* __restrict__ hs,
             unsigned int* flags)
{
    __shared__ ushort As[16 * 1536];   // 48 KB A tile, ^(row&15) swizzled (0 conflicts)
    __shared__ float  scr[8][16][17];  // 8.5 KB K-half reduction, padded

    const int tid  = threadIdx.x;
    const int lane = tid & 63;
    const int wv   = tid >> 6;        // 0..15
    const int nh   = wv & 7;          // n-subtile: cols [nh*16, +16)
    const int kh   = wv >> 3;         // K-half (even/odd chunk interleave)
    const int bx   = blockIdx.x;
    const int grp  = bx & 7;          // group (XCD-affine under bx%8 round-robin)
    const int sub  = bx >> 3;         // 0..31 within group
    const int nbase = sub * 128;      // block's gate-col base
    const int rbase = grp * 16;       // group's batch-row base

    const int colg  = nbase + nh * 16 + (lane & 15);  // this lane's gate column
    const int g     = lane & 3;                       // gate id (f,i,c~,o)
    const int unitg = colg >> 2;                      // global hidden unit

    // ---- persistent W fragments: breg[r] covers chunk c = 2r+kh, k = c*32 ----
    bf16x8 breg[24];
#pragma unroll
    for (int r = 0; r < 24; ++r)
        breg[r] = *(const bf16x8*)(Wcat + (size_t)colg * KC_
                                   + (2 * r + kh) * 32 + (lane >> 4) * 8);
#pragma unroll
    for (int r = 0; r < 24; ++r) {    // pin against rematerialization
        f32x4 tmp = __builtin_bit_cast(f32x4, breg[r]);
        asm volatile("" : "+v"(tmp));
        breg[r] = __builtin_bit_cast(bf16x8, tmp);
    }

    const float biasv = bias[colg];
    float creg4[4] = {0.f, 0.f, 0.f, 0.f};   // kh=0 waves: c for rows (lane>>4)*4+q

    const int srow = tid >> 6;        // staging row == wave id (wave stages one row)
    const int sc64 = tid & 63;        // staging lane
    const int arow = lane & 15;       // A-frag row

    for (int t = 0; t < T_; ++t) {
        // ---- stage x-part: 1 uint4 per thread (barrier-independent) ----
        const ushort* xTt = xT + ((size_t)t * B_ + rbase) * IN_;
        {
            uint4 vx = *(const uint4*)(xTt + (size_t)srow * IN_ + sc64 * 8);
            *(uint4*)&As[srow * 1536 + (sc64 ^ (srow & 15)) * 8] = vx;
        }
        __syncthreads();

        // ---- x-part MFMAs (chunks 2r+kh < 16, i.e. r < 8) before barrier ----
        f32x4 accs[2];
        accs[0] = (f32x4){0.f, 0.f, 0.f, 0.f};
        accs[1] = (f32x4){0.f, 0.f, 0.f, 0.f};
#pragma unroll
        for (int r = 0; r < 8; ++r) {
            const int s = (2 * r + kh) * 4 + (lane >> 4);
            bf16x8 a = *(const bf16x8*)&As[arow * 1536 + (s ^ (arow & 15)) * 8];
            accs[r & 1] = mfma16(a, breg[r], accs[r & 1]);
        }

        // ---- group barrier: poll 32 flags (relaxed agent = LLC-fresh) ----
        if (t > 0 && wv == 0) {
            const bool active = lane < 32;
            const unsigned int* fp = flags + (lane & 31) * 8 + grp;
            while (1) {
                unsigned v = active
                    ? __hip_atomic_load(fp, __ATOMIC_RELAXED, __HIP_MEMORY_SCOPE_AGENT)
                    : ~0u;
                if (__ballot(active && v < (unsigned)t) == 0ull) break;
                __builtin_amdgcn_s_sleep(1);
            }
        }
        __syncthreads();

        // ---- stage h-part via LLC-coherent dword loads: 8 dwords/thread ----
        const unsigned int* hrow =
            (const unsigned int*)(hs + ((size_t)t * B_ + rbase + srow) * H_);
#pragma unroll
        for (int jb = 0; jb < 2; ++jb) {
            unsigned int hv[4];
#pragma unroll
            for (int j = 0; j < 4; ++j)
                hv[j] = __hip_atomic_load(hrow + (jb * 4 + j) * 64 + sc64,
                                          __ATOMIC_RELAXED, __HIP_MEMORY_SCOPE_AGENT);
#pragma unroll
            for (int j = 0; j < 4; ++j) {
                const int d = (jb * 4 + j) * 64 + sc64;       // dword 0..511 in row
                const int z = d >> 2;                          // h-seg 0..127
                *(unsigned int*)&As[srow * 1536 + ((64 + z) ^ (srow & 15)) * 8
                                    + (d & 3) * 2] = hv[j];
            }
        }
        __syncthreads();

        // ---- h-part MFMAs (chunks 2r+kh >= 16, r = 8..23) ----
#pragma unroll
        for (int r = 8; r < 24; ++r) {
            const int s = (2 * r + kh) * 4 + (lane >> 4);
            bf16x8 a = *(const bf16x8*)&As[arow * 1536 + (s ^ (arow & 15)) * 8];
            accs[r & 1] = mfma16(a, breg[r], accs[r & 1]);
        }
        f32x4 acc = accs[0] + accs[1];

        // ---- cross-kh reduction ----
        if (kh == 1) {
#pragma unroll
            for (int q = 0; q < 4; ++q)
                scr[nh][(lane >> 4) * 4 + q][lane & 15] = acc[q];
        }
        __syncthreads();

        // ---- gate epilogue (kh=0 waves): quad-lane exchange, LLC h stores ----
        if (kh == 0) {
            unsigned int* hout =
                (unsigned int*)(hs + ((size_t)(t + 1) * B_ + rbase) * H_);
#pragma unroll
            for (int q = 0; q < 4; ++q) {
                const int row = (lane >> 4) * 4 + q;
                float v = acc[q] + scr[nh][row][lane & 15] + biasv;
                float a0 = (g == 2) ? tanhf(v) : sigf(v);   // own gate activated
                float a1 = __shfl_xor(a0, 1);
                float a2 = __shfl_xor(a0, 2);
                float a3 = __shfl_xor(a1, 2);               // lane^3
                float vf = (g == 0) ? a0 : (g == 1) ? a1 : (g == 2) ? a2 : a3;
                float vi = (g == 0) ? a1 : (g == 1) ? a0 : (g == 2) ? a3 : a2;
                float vc = (g == 0) ? a2 : (g == 1) ? a3 : (g == 2) ? a0 : a1;
                float vo = (g == 0) ? a3 : (g == 1) ? a2 : (g == 2) ? a1 : a0;
                float cn = vf * creg4[q] + vi * vc;
                creg4[q] = cn;
                unsigned int hu = (unsigned int)f2bf(vo * tanhf(cn));
                unsigned int hp = (unsigned int)__shfl_xor((int)hu, 4);
                if ((lane & 7) == 0)
                    __hip_atomic_store(hout + row * 512 + (unitg >> 1),
                                       hu | (hp << 16),
                                       __ATOMIC_RELAXED, __HIP_MEMORY_SCOPE_AGENT);
            }
        }
        __syncthreads();   // drains vmcnt(0): all h stores LLC-visible
        if (tid == 0)
            __hip_atomic_store(flags + bx, (unsigned)(t + 1), __ATOMIC_RELAXED,
                               __HIP_MEMORY_SCOPE_AGENT);
    }
}

// ---------------- output projection GEMM ----------------

__launch_bounds__(256, 2)
__global__ void out_gemm(const ushort* __restrict__ hsflat,
                         const ushort* __restrict__ Wout,
                         const float* __restrict__ bout,
                         float* __restrict__ out)
{
    __shared__ ushort As2[128 * 64];
    __shared__ ushort Bs2[64 * 64];
    const int tid  = threadIdx.x;
    const int lane = tid & 63;
    const int wave = tid >> 6;
    const int wm = (wave >> 1) * 64;
    const int wn = (wave & 1) * 32;
    const int mbase = (blockIdx.x >> 3) * 128;
    const int nbase = (blockIdx.x & 7) * 64;

    f32x4 acc[4][2];
#pragma unroll
    for (int i = 0; i < 4; i++)
#pragma unroll
        for (int j = 0; j < 2; j++) acc[i][j] = (f32x4){0.f, 0.f, 0.f, 0.f};

    for (int kc = 0; kc < H_ / 64; ++kc) {
        const int k0 = kc * 64;
        __syncthreads();
#pragma unroll
        for (int it = 0; it < 4; ++it) {
            int g = it * 256 + tid;
            int row = g >> 3;
            int seg = g & 7;
            uint4 v = *(const uint4*)(hsflat + (size_t)(mbase + row) * H_ + k0 + seg * 8);
            int dstg = seg ^ (row & 7);
            *(uint4*)&As2[row * 64 + dstg * 8] = v;
        }
#pragma unroll
        for (int it = 0; it < 2; ++it) {
            int g = it * 256 + tid;
            int row = g >> 3;
            int seg = g & 7;
            uint4 v = *(const uint4*)(Wout + (size_t)(nbase + row) * H_ + k0 + seg * 8);
            int dstg = seg ^ (row & 7);
            *(uint4*)&Bs2[row * 64 + dstg * 8] = v;
        }
        __syncthreads();
#pragma unroll
        for (int ks = 0; ks < 2; ++ks) {
            const int kg = ks * 4 + (lane >> 4);
            bf16x8 af[4], bfr[2];
#pragma unroll
            for (int mi = 0; mi < 4; ++mi) {
                int row = wm + mi * 16 + (lane & 15);
                int gi = kg ^ (row & 7);
                af[mi] = *(const bf16x8*)&As2[row * 64 + gi * 8];
            }
#pragma unroll
            for (int ni = 0; ni < 2; ++ni) {
                int row = wn + ni * 16 + (lane & 15);
                int gi = kg ^ (row & 7);
                bfr[ni] = *(const bf16x8*)&Bs2[row * 64 + gi * 8];
            }
#pragma unroll
            for (int mi = 0; mi < 4; ++mi)
#pragma unroll
                for (int ni = 0; ni < 2; ++ni)
                    acc[mi][ni] = mfma16(af[mi], bfr[ni], acc[mi][ni]);
        }
    }

#pragma unroll
    for (int mi = 0; mi < 4; ++mi) {
#pragma unroll
        for (int ni = 0; ni < 2; ++ni) {
            int col = nbase + wn + ni * 16 + (lane & 15);
            float bv = bout[col];
#pragma unroll
            for (int q = 0; q < 4; ++q) {
                int rt = mbase + wm + mi * 16 + (lane >> 4) * 4 + q;
                int b = rt & 127, tt = rt >> 7;
                out[((size_t)b * T_ + tt) * OUT_ + col] = acc[mi][ni][q] + bv;
            }
        }
    }
}

// ---------------- launcher ----------------

extern "C" void kernel_launch(void* const* d_in, const int* in_sizes, int n_in,
                              void* d_out, int out_size, void* d_ws, size_t ws_size,
                              hipStream_t stream)
{
    const float* x    = (const float*)d_in[0];
    const float* Wf   = (const float*)d_in[1];
    const float* bf_  = (const float*)d_in[2];
    const float* Wi   = (const float*)d_in[3];
    const float* bi_  = (const float*)d_in[4];
    const float* Wc   = (const float*)d_in[5];
    const float* bc_  = (const float*)d_in[6];
    const float* Wo   = (const float*)d_in[7];
    const float* bo_  = (const float*)d_in[8];
    const float* Wout = (const float*)d_in[9];
    const float* bout = (const float*)d_in[10];
    float* out = (float*)d_out;

    char* ws = (char*)d_ws;
    size_t off = 0;
    auto alloc = [&](size_t bytes) {
        char* p = ws + off;
        off += (bytes + 255) & ~(size_t)255;
        return p;
    };
    ushort* xT   = (ushort*)alloc((size_t)T_ * B_ * IN_ * 2);       // 33.6 MB
    ushort* Wcat = (ushort*)alloc((size_t)NG_ * KC_ * 2);           // 12.6 MB
    float*  bias = (float*) alloc((size_t)NG_ * 4);
    ushort* Wob  = (ushort*)alloc((size_t)OUT_ * H_ * 2);           // 1 MB
    ushort* hs   = (ushort*)alloc((size_t)(T_ + 1) * B_ * H_ * 2);  // 67.4 MB
    unsigned int* flags = (unsigned int*)alloc((size_t)NBLK * 4);

    hipLaunchKernelGGL(prep_w,    dim3(NG_), dim3(256), 0, stream, Wf, Wi, Wc, Wo, Wcat);
    hipLaunchKernelGGL(prep_bias, dim3(16),  dim3(256), 0, stream, bf_, bi_, bc_, bo_, bias);
    hipLaunchKernelGGL(prep_wout, dim3(OUT_),dim3(256), 0, stream, Wout, Wob);
    hipLaunchKernelGGL(prep_x,    dim3(T_ * B_), dim3(256), 0, stream, x, xT);
    hipLaunchKernelGGL(prep_zero, dim3(512), dim3(256), 0, stream, hs, flags);

    hipLaunchKernelGGL(lstm_persist, dim3(NBLK), dim3(NTHR), 0, stream,
                       xT, Wcat, bias, hs, flags);

    hipLaunchKernelGGL(out_gemm, dim3(2048), dim3(256), 0, stream,
                       hs + (size_t)B_ * H_, Wob, bout, out);
}

// Round 9
// 1627.355 us; speedup vs baseline: 1.5528x; 1.5528x over previous
//
#include <hip/hip_runtime.h>
#include <stdint.h>

#define B_   128
#define T_   256
#define IN_  512
#define H_   1024
#define NG_  4096   // 4*H (gate-interleaved cols)
#define KC_  1536   // IN+H
#define OUT_ 512
#define NBLK 256    // 4 groups x 64 blocks; XCD x hosts subs {x,x+8,...,x+56}
#define NTHR 512

typedef __bf16 bf16x8 __attribute__((ext_vector_type(8)));
typedef float  f32x4  __attribute__((ext_vector_type(4)));
typedef unsigned long long ull;

__device__ __forceinline__ ushort f2bf(float f) {
    union { float f; uint32_t u; } v; v.f = f;
    uint32_t u = v.u;
    return (ushort)((u + 0x7FFFu + ((u >> 16) & 1u)) >> 16);  // RNE
}

__device__ __forceinline__ f32x4 mfma16(bf16x8 a, bf16x8 b, f32x4 c) {
    return __builtin_amdgcn_mfma_f32_16x16x32_bf16(a, b, c, 0, 0, 0);
}

__device__ __forceinline__ float sigf(float x) {
    return 1.f / (1.f + __expf(-x));
}

// ---------------- prep kernels ----------------
// Wcat2 layout: [k-chunk c][gate-col][k&31] — a wave's 16-col x 32-k W-frag
// is one dense, perfectly coalesced 1KB block.

__global__ void prep_w(const float* __restrict__ Wf, const float* __restrict__ Wi,
                       const float* __restrict__ Wc, const float* __restrict__ Wo,
                       ushort* __restrict__ Wc2) {
    int col = blockIdx.x;            // 0..4095 (= 4*j+g)
    int j = col >> 2, g = col & 3;
    const float* W = (g == 0) ? Wf : (g == 1) ? Wi : (g == 2) ? Wc : Wo;
    for (int k = threadIdx.x; k < KC_; k += 256)
        Wc2[((size_t)(k >> 5) * NG_ + col) * 32 + (k & 31)] = f2bf(W[(size_t)j * KC_ + k]);
}

__global__ void prep_bias(const float* __restrict__ bf_, const float* __restrict__ bi_,
                          const float* __restrict__ bc_, const float* __restrict__ bo_,
                          float* __restrict__ bias) {
    int idx = blockIdx.x * 256 + threadIdx.x;  // 16 blocks -> 4096
    int j = idx >> 2, g = idx & 3;
    const float* b = (g == 0) ? bf_ : (g == 1) ? bi_ : (g == 2) ? bc_ : bo_;
    bias[idx] = b[j];
}

__global__ void prep_wout(const float* __restrict__ W, ushort* __restrict__ Wb) {
    int row = blockIdx.x;  // 512
    for (int k = threadIdx.x; k < H_; k += 256)
        Wb[(size_t)row * H_ + k] = f2bf(W[(size_t)row * H_ + k]);
}

__global__ void prep_x(const float* __restrict__ x, ushort* __restrict__ xT) {
    int bid = blockIdx.x;            // t*128 + b
    int t = bid >> 7, b = bid & 127;
    const float* src = x  + ((size_t)b * T_ + t) * IN_;
    ushort*      dst = xT + ((size_t)t * B_ + b) * IN_;
    for (int k = threadIdx.x; k < IN_; k += 256) dst[k] = f2bf(src[k]);
}

__global__ void prep_zero(ushort* __restrict__ hs0, unsigned int* __restrict__ flags) {
    int idx = blockIdx.x * 256 + threadIdx.x;  // 512*256 = 131072 = B_*H_
    hs0[idx] = 0;
    if (idx < NBLK) flags[idx] = 0u;
}

// ---------------- persistent LSTM kernel ----------------
// 256 blocks x 512 threads (8 waves), 1 block/CU (LDS 105KB). Decomposition:
// grp = (bx>>3)&3 owns batch rows [grp*32,+32); sub = (bx&7)+8*(bx>>5) owns
// gate cols [sub*64,+64). Under the bx%8->XCD round-robin heuristic, XCD x
// hosts exactly subs {x,x+8,..,x+56}: W working set/XCD = 8 x 192KB = 1.5MB,
// resident in that XCD's 4MB L2 -> W streams from LOCAL L2 every step.
// r2-r7 lesson: W-in-VGPRs is unwinnable (allocator granted 92/128/128/128/64
// and remat'd or spilled); so W is now a 4-deep rolling prefetch stream
// (16 VGPRs), total ~80 VGPRs. Wave wv: nf=wv&3 (16 cols), kh=wv>>2 (even/odd
// k-chunks interleaved so x-part balances). Coherence (r5, unchanged): NO
// acquire/release fences (would evict the L2-resident W!); h + flags via
// relaxed agent-scope atomics (LLC-coherent, L1/L2 bypass); ordering =
// syncthreads vmcnt-drain before flag store + reader control-dep on flag.

__launch_bounds__(NTHR, 2)
__global__ void lstm_persist(const ushort* __restrict__ xT,
                             const ushort* __restrict__ Wc2,
                             const float* __restrict__ bias,
                             ushort* __restrict__ hs,
                             unsigned int* flags)
{
    __shared__ ushort As[32 * 1536];      // 96 KB A tile, ^(row&15) swizzled
    __shared__ float  scr[4][2][16][17];  // 8.7 KB K-half reduction, padded

    const int tid  = threadIdx.x;
    const int lane = tid & 63;
    const int wv   = tid >> 6;        // 0..7
    const int nf   = wv & 3;          // n-subtile: 16 cols
    const int kh   = wv >> 2;         // k-half (even/odd chunk interleave)
    const int bx   = blockIdx.x;
    const int grp  = (bx >> 3) & 3;   // batch group (rows)
    const int sub  = (bx & 7) + 8 * (bx >> 5);  // gate-col tile, XCD-affine
    const int nbase = sub * 64;
    const int rbase = grp * 32;

    const int colg  = nbase + nf * 16 + (lane & 15);  // this lane's gate column
    const int g     = lane & 3;                       // gate id (f,i,c~,o)
    const int unitg = colg >> 2;                      // global hidden unit

    const float biasv = bias[colg];
    float creg[2][4] = {{0.f,0.f,0.f,0.f},{0.f,0.f,0.f,0.f}};

    const int srow = tid >> 4;        // staging row 0..31 (16 threads/row)
    const int sc16 = tid & 15;
    const int arow0 = lane & 15;      // A-frag rows (m=0/1)
    const int arow1 = 16 + (lane & 15);
    const int asw  = lane & 15;       // swizzle key (same for both rows)

    const ushort* wbase = Wc2 + (size_t)colg * 32 + (lane >> 4) * 8;

    for (int t = 0; t < T_; ++t) {
        // ---- stage x-part (cached loads; barrier-independent) ----
        const ushort* xTt = xT + ((size_t)t * B_ + rbase + srow) * IN_;
#pragma unroll
        for (int j = 0; j < 4; ++j) {
            const int s = j * 16 + sc16;              // seg 0..63
            uint4 v = *(const uint4*)(xTt + s * 8);
            *(uint4*)&As[srow * 1536 + (s ^ (srow & 15)) * 8] = v;
        }
        __syncthreads();

        // ---- x-part k-loop (chunks c = 2i+kh < 16), rolling W prefetch.
        //      loads for i=8..11 (h-part W) are issued here too: they do not
        //      depend on h and overlap the barrier wait/drain. ----
        f32x4 acc0 = {0.f,0.f,0.f,0.f}, acc1 = {0.f,0.f,0.f,0.f};
        bf16x8 wf[4];
#pragma unroll
        for (int i = 0; i < 4; ++i)
            wf[i] = *(const bf16x8*)(wbase + (size_t)(2 * i + kh) * (NG_ * 32));
#pragma unroll
        for (int i = 0; i < 8; ++i) {
            const int c  = 2 * i + kh;
            const int ks = c * 4 + (lane >> 4);
            bf16x8 a0 = *(const bf16x8*)&As[arow0 * 1536 + (ks ^ asw) * 8];
            bf16x8 a1 = *(const bf16x8*)&As[arow1 * 1536 + (ks ^ asw) * 8];
            bf16x8 w = wf[i & 3];
            wf[i & 3] = *(const bf16x8*)(wbase + (size_t)(2 * (i + 4) + kh) * (NG_ * 32));
            acc0 = mfma16(a0, w, acc0);
            acc1 = mfma16(a1, w, acc1);
        }

        // ---- group barrier: poll the 64 flags of this group's blocks ----
        if (t > 0 && wv == 0) {
            const unsigned int* fp =
                flags + (lane & 7) + 8 * grp + 32 * (lane >> 3);
            while (1) {
                unsigned v = __hip_atomic_load(fp, __ATOMIC_RELAXED,
                                               __HIP_MEMORY_SCOPE_AGENT);
                if (__ballot(v < (unsigned)t) == 0ull) break;
                __builtin_amdgcn_s_sleep(1);
            }
        }
        __syncthreads();

        // ---- stage h-part via LLC-coherent 8B atomic loads ----
        const ull* hrow = (const ull*)(hs + ((size_t)t * B_ + rbase + srow) * H_);
#pragma unroll
        for (int jb = 0; jb < 2; ++jb) {
            ull hv[8];
#pragma unroll
            for (int j = 0; j < 8; ++j)
                hv[j] = __hip_atomic_load(hrow + (jb * 8 + j) * 16 + sc16,
                                          __ATOMIC_RELAXED, __HIP_MEMORY_SCOPE_AGENT);
#pragma unroll
            for (int j = 0; j < 8; ++j) {
                const int jj  = jb * 8 + j;                    // 0..15
                const int seg = 64 + jj * 8 + (sc16 >> 1);     // 64..191
                *(ull*)&As[srow * 1536 + (seg ^ (srow & 15)) * 8 + (sc16 & 1) * 4]
                    = hv[j];
            }
        }
        __syncthreads();

        // ---- h-part k-loop (chunks c = 2i+kh >= 16) ----
#pragma unroll
        for (int i = 8; i < 24; ++i) {
            const int c  = 2 * i + kh;
            const int ks = c * 4 + (lane >> 4);
            bf16x8 a0 = *(const bf16x8*)&As[arow0 * 1536 + (ks ^ asw) * 8];
            bf16x8 a1 = *(const bf16x8*)&As[arow1 * 1536 + (ks ^ asw) * 8];
            bf16x8 w = wf[i & 3];
            if (i < 20)
                wf[i & 3] = *(const bf16x8*)(wbase + (size_t)(2 * (i + 4) + kh) * (NG_ * 32));
            acc0 = mfma16(a0, w, acc0);
            acc1 = mfma16(a1, w, acc1);
        }

        // ---- cross-kh reduction ----
        if (kh == 1) {
#pragma unroll
            for (int q = 0; q < 4; ++q) {
                scr[nf][0][(lane >> 4) * 4 + q][lane & 15] = acc0[q];
                scr[nf][1][(lane >> 4) * 4 + q][lane & 15] = acc1[q];
            }
        }
        __syncthreads();

        // ---- gate epilogue (kh=0 waves): quad-lane exchange, LLC h stores ----
        if (kh == 0) {
            unsigned int* hout =
                (unsigned int*)(hs + ((size_t)(t + 1) * B_ + rbase) * H_);
#pragma unroll
            for (int mf = 0; mf < 2; ++mf) {
#pragma unroll
                for (int q = 0; q < 4; ++q) {
                    const int r16 = (lane >> 4) * 4 + q;
                    const int row = mf * 16 + r16;
                    float v = (mf ? acc1[q] : acc0[q])
                            + scr[nf][mf][r16][lane & 15] + biasv;
                    float a0 = (g == 2) ? tanhf(v) : sigf(v);   // own gate
                    float a1 = __shfl_xor(a0, 1);
                    float a2 = __shfl_xor(a0, 2);
                    float a3 = __shfl_xor(a1, 2);               // lane^3
                    float vf = (g == 0) ? a0 : (g == 1) ? a1 : (g == 2) ? a2 : a3;
                    float vi = (g == 0) ? a1 : (g == 1) ? a0 : (g == 2) ? a3 : a2;
                    float vc = (g == 0) ? a2 : (g == 1) ? a3 : (g == 2) ? a0 : a1;
                    float vo = (g == 0) ? a3 : (g == 1) ? a2 : (g == 2) ? a1 : a0;
                    float cn = vf * creg[mf][q] + vi * vc;
                    creg[mf][q] = cn;
                    unsigned int hu = (unsigned int)f2bf(vo * tanhf(cn));
                    unsigned int hp = (unsigned int)__shfl_xor((int)hu, 4);
                    if ((lane & 7) == 0)
                        __hip_atomic_store(hout + row * 512 + (unitg >> 1),
                                           hu | (hp << 16),
                                           __ATOMIC_RELAXED, __HIP_MEMORY_SCOPE_AGENT);
                }
            }
        }
        __syncthreads();   // drains vmcnt(0): all h stores LLC-visible
        if (tid == 0)
            __hip_atomic_store(flags + bx, (unsigned)(t + 1), __ATOMIC_RELAXED,
                               __HIP_MEMORY_SCOPE_AGENT);
    }
}

// ---------------- output projection GEMM ----------------

__launch_bounds__(256, 2)
__global__ void out_gemm(const ushort* __restrict__ hsflat,
                         const ushort* __restrict__ Wout,
                         const float* __restrict__ bout,
                         float* __restrict__ out)
{
    __shared__ ushort As2[128 * 64];
    __shared__ ushort Bs2[64 * 64];
    const int tid  = threadIdx.x;
    const int lane = tid & 63;
    const int wave = tid >> 6;
    const int wm = (wave >> 1) * 64;
    const int wn = (wave & 1) * 32;
    const int mbase = (blockIdx.x >> 3) * 128;
    const int nbase = (blockIdx.x & 7) * 64;

    f32x4 acc[4][2];
#pragma unroll
    for (int i = 0; i < 4; i++)
#pragma unroll
        for (int j = 0; j < 2; j++) acc[i][j] = (f32x4){0.f, 0.f, 0.f, 0.f};

    for (int kc = 0; kc < H_ / 64; ++kc) {
        const int k0 = kc * 64;
        __syncthreads();
#pragma unroll
        for (int it = 0; it < 4; ++it) {
            int gg = it * 256 + tid;
            int row = gg >> 3;
            int seg = gg & 7;
            uint4 v = *(const uint4*)(hsflat + (size_t)(mbase + row) * H_ + k0 + seg * 8);
            int dstg = seg ^ (row & 7);
            *(uint4*)&As2[row * 64 + dstg * 8] = v;
        }
#pragma unroll
        for (int it = 0; it < 2; ++it) {
            int gg = it * 256 + tid;
            int row = gg >> 3;
            int seg = gg & 7;
            uint4 v = *(const uint4*)(Wout + (size_t)(nbase + row) * H_ + k0 + seg * 8);
            int dstg = seg ^ (row & 7);
            *(uint4*)&Bs2[row * 64 + dstg * 8] = v;
        }
        __syncthreads();
#pragma unroll
        for (int ks = 0; ks < 2; ++ks) {
            const int kg = ks * 4 + (lane >> 4);
            bf16x8 af[4], bfr[2];
#pragma unroll
            for (int mi = 0; mi < 4; ++mi) {
                int row = wm + mi * 16 + (lane & 15);
                int gi = kg ^ (row & 7);
                af[mi] = *(const bf16x8*)&As2[row * 64 + gi * 8];
            }
#pragma unroll
            for (int ni = 0; ni < 2; ++ni) {
                int row = wn + ni * 16 + (lane & 15);
                int gi = kg ^ (row & 7);
                bfr[ni] = *(const bf16x8*)&Bs2[row * 64 + gi * 8];
            }
#pragma unroll
            for (int mi = 0; mi < 4; ++mi)
#pragma unroll
                for (int ni = 0; ni < 2; ++ni)
                    acc[mi][ni] = mfma16(af[mi], bfr[ni], acc[mi][ni]);
        }
    }

#pragma unroll
    for (int mi = 0; mi < 4; ++mi) {
#pragma unroll
        for (int ni = 0; ni < 2; ++ni) {
            int col = nbase + wn + ni * 16 + (lane & 15);
            float bv = bout[col];
#pragma unroll
            for (int q = 0; q < 4; ++q) {
                int rt = mbase + wm + mi * 16 + (lane >> 4) * 4 + q;
                int b = rt & 127, tt = rt >> 7;
                out[((size_t)b * T_ + tt) * OUT_ + col] = acc[mi][ni][q] + bv;
            }
        }
    }
}

// ---------------- launcher ----------------

extern "C" void kernel_launch(void* const* d_in, const int* in_sizes, int n_in,
                              void* d_out, int out_size, void* d_ws, size_t ws_size,
                              hipStream_t stream)
{
    const float* x    = (const float*)d_in[0];
    const float* Wf   = (const float*)d_in[1];
    const float* bf_  = (const float*)d_in[2];
    const float* Wi   = (const float*)d_in[3];
    const float* bi_  = (const float*)d_in[4];
    const float* Wc   = (const float*)d_in[5];
    const float* bc_  = (const float*)d_in[6];
    const float* Wo   = (const float*)d_in[7];
    const float* bo_  = (const float*)d_in[8];
    const float* Wout = (const float*)d_in[9];
    const float* bout = (const float*)d_in[10];
    float* out = (float*)d_out;

    char* ws = (char*)d_ws;
    size_t off = 0;
    auto alloc = [&](size_t bytes) {
        char* p = ws + off;
        off += (bytes + 255) & ~(size_t)255;
        return p;
    };
    ushort* xT   = (ushort*)alloc((size_t)T_ * B_ * IN_ * 2);       // 33.6 MB
    ushort* Wc2  = (ushort*)alloc((size_t)NG_ * KC_ * 2);           // 12.6 MB
    float*  bias = (float*) alloc((size_t)NG_ * 4);
    ushort* Wob  = (ushort*)alloc((size_t)OUT_ * H_ * 2);           // 1 MB
    ushort* hs   = (ushort*)alloc((size_t)(T_ + 1) * B_ * H_ * 2);  // 67.4 MB
    unsigned int* flags = (unsigned int*)alloc((size_t)NBLK * 4);

    hipLaunchKernelGGL(prep_w,    dim3(NG_), dim3(256), 0, stream, Wf, Wi, Wc, Wo, Wc2);
    hipLaunchKernelGGL(prep_bias, dim3(16),  dim3(256), 0, stream, bf_, bi_, bc_, bo_, bias);
    hipLaunchKernelGGL(prep_wout, dim3(OUT_),dim3(256), 0, stream, Wout, Wob);
    hipLaunchKernelGGL(prep_x,    dim3(T_ * B_), dim3(256), 0, stream, x, xT);
    hipLaunchKernelGGL(prep_zero, dim3(512), dim3(256), 0, stream, hs, flags);

    hipLaunchKernelGGL(lstm_persist, dim3(NBLK), dim3(NTHR), 0, stream,
                       xT, Wc2, bias, hs, flags);

    hipLaunchKernelGGL(out_gemm, dim3(2048), dim3(256), 0, stream,
                       hs + (size_t)B_ * H_, Wob, bout, out);
}